// Round 6
// baseline (312.129 us; speedup 1.0000x reference)
//
#include <hip/hip_runtime.h>
#include <hip/hip_cooperative_groups.h>

namespace cg = cooperative_groups;

static constexpr int N_NODES = 100000;
static constexpr int N_EDGES = 10000;
static constexpr int NNZ     = 1600000;

static constexpr int G       = 256;          // grid blocks (1/CU guaranteed resident)
static constexpr int BLK     = 1024;
static constexpr int CHUNK   = NNZ / G;      // 6250
static constexpr int NR      = 8;            // node ranges
static constexpr int RANGE   = 12500;        // nodes per range
static constexpr int CAP     = 204800;       // per-range binned capacity (mean 200K, 11.5 sigma margin)
static constexpr int M_NODE  = 32;           // node blocks per range (NR*M_NODE = G)
static constexpr int EBLKS   = (N_EDGES + 63) / 64;  // 157 edge-reduce blocks

// ---------------- ws layout (bytes), ~38.4 MB of ~256 MiB ----------------
// binned @ 0          : NR*CAP u32            = 6,553,600
// cursor @ 6,553,600  : NR u32 (memset 0)
// P_S    @ 6,553,664  : G*N_EDGES f           = 10,240,000
// P_B    @ +10,240,000: G*(N_EDGES/2) u32     =  5,120,000
// PS_n   @ +15,360,000: G*RANGE f             = 12,800,000
// PC_n   @ +28,160,000: G*(RANGE/4) u32       =  3,200,000
// smalls @ +31,360,000: Binv(10K) v1(10K) v2(10K) Dinv(100K) y(100K) floats

__global__ __launch_bounds__(BLK) void k_mega(
        const int* __restrict__ nidx, const int* __restrict__ eidx,
        const float* __restrict__ x,
        const float* __restrict__ W1, const float* __restrict__ b1,
        const float* __restrict__ W2, const float* __restrict__ b2,
        unsigned* __restrict__ cursor, unsigned* __restrict__ binned,
        float* __restrict__ P_S, unsigned* __restrict__ P_B,
        float* __restrict__ PS_n, unsigned* __restrict__ PC_n,
        float* __restrict__ Binv, float* __restrict__ v1, float* __restrict__ v2,
        float* __restrict__ Dinv, float* __restrict__ y,
        float* __restrict__ out) {
    cg::grid_group grid = cg::this_grid();
    __shared__ union {
        struct { float sS[N_EDGES]; unsigned sC[N_EDGES / 2]; unsigned cnt[NR]; unsigned base[NR]; } e;  // 60,064 B
        struct { float sS[RANGE]; unsigned sC[RANGE / 4]; } n;                                           // 62,500 B
        struct { float w[384]; float redS[16][64]; unsigned redC[16][64]; } m;                           //  9,728 B
    } sm;

    const int b = blockIdx.x;
    const int t = threadIdx.x;

    // ============ Phase 0: fused bin + edge-agg-1 (single scan of nidx/eidx) ======
    for (int j = t; j < N_EDGES; j += BLK) sm.e.sS[j] = 0.0f;
    for (int j = t; j < N_EDGES / 2; j += BLK) sm.e.sC[j] = 0u;
    if (t < NR) sm.e.cnt[t] = 0u;
    __syncthreads();
    {
        const int i0 = b * CHUNK, i1 = i0 + CHUNK;
        for (int i = i0 + t; i < i1; i += BLK) {
            int n = nidx[i];
            int e = eidx[i];
            atomicAdd(&sm.e.sS[e], x[n]);
            atomicAdd(&sm.e.sC[e >> 1], 1u << ((e & 1) * 16));  // <=6250/block, u16 safe
            atomicAdd(&sm.e.cnt[n / RANGE], 1u);
        }
        __syncthreads();
        if (t < NR) {
            sm.e.base[t] = atomicAdd(&cursor[t], sm.e.cnt[t]);
            sm.e.cnt[t] = 0u;
        }
        __syncthreads();
        for (int i = i0 + t; i < i1; i += BLK) {   // chunk re-read is L1/L2-hot
            int n = nidx[i];
            int e = eidx[i];
            int r = n / RANGE;
            unsigned p = sm.e.base[r] + atomicAdd(&sm.e.cnt[r], 1u);
            binned[(size_t)r * CAP + p] = ((unsigned)(n - r * RANGE) << 14) | (unsigned)e;
        }
        __syncthreads();
        float*    ps = P_S + (size_t)b * N_EDGES;
        unsigned* pb = P_B + (size_t)b * (N_EDGES / 2);
        for (int j = t; j < N_EDGES; j += BLK) ps[j] = sm.e.sS[j];
        for (int j = t; j < N_EDGES / 2; j += BLK) pb[j] = sm.e.sC[j];
    }
    grid.sync();

    // ============ Phase 1: edge reduce 1 -> Binv, v1 ============
    if (b < EBLKS) {
        const int eo = t & 63, sl = t >> 6;    // 16 slices x 64 edges
        const int e = b * 64 + eo;
        float s = 0.0f; unsigned c = 0u;
        if (e < N_EDGES) {
            for (int g = sl; g < G; g += 16) {
                s += P_S[(size_t)g * N_EDGES + e];
                c += (P_B[(size_t)g * (N_EDGES / 2) + (e >> 1)] >> ((e & 1) * 16)) & 0xFFFFu;
            }
        }
        sm.m.redS[sl][eo] = s;
        sm.m.redC[sl][eo] = c;
        __syncthreads();
        if (sl == 0 && e < N_EDGES) {
            float ss = 0.0f; unsigned cc = 0u;
            #pragma unroll
            for (int k = 0; k < 16; ++k) { ss += sm.m.redS[k][eo]; cc += sm.m.redC[k][eo]; }
            float binv = (cc > 0u) ? (1.0f / (float)cc) : 0.0f;
            Binv[e] = binv;
            v1[e]   = ss * binv;
        }
    }
    grid.sync();

    // ============ Phase 2: node pass 1 (binned, LDS-privatized) ============
    {
        const int r  = b >> 5;          // / M_NODE
        const int mb = b & 31;
        for (int j = t; j < RANGE; j += BLK) sm.n.sS[j] = 0.0f;
        for (int j = t; j < RANGE / 4; j += BLK) sm.n.sC[j] = 0u;
        __syncthreads();
        const int cnt = (int)cursor[r];
        const int sub = (cnt + M_NODE - 1) >> 5;
        const int p0 = mb * sub;
        const int p1 = min(p0 + sub, cnt);
        const unsigned* src = binned + (size_t)r * CAP;
        for (int i = p0 + t; i < p1; i += BLK) {
            unsigned w = src[i];
            unsigned l = w >> 14;
            atomicAdd(&sm.n.sS[l], v1[w & 0x3FFFu]);
            atomicAdd(&sm.n.sC[l >> 2], 1u << ((l & 3) * 8));   // u8: per-node deg < 255
        }
        __syncthreads();
        float*    ps = PS_n + (size_t)b * RANGE;
        unsigned* pc = PC_n + (size_t)b * (RANGE / 4);
        for (int j = t; j < RANGE; j += BLK) ps[j] = sm.n.sS[j];
        for (int j = t; j < RANGE / 4; j += BLK) pc[j] = sm.n.sC[j];
    }
    grid.sync();

    // ============ Phase 3: node reduce + 128-wide MLP -> Dinv, y ============
    if (t < 128) {
        sm.m.w[t]       = W1[t];
        sm.m.w[128 + t] = b1[t];
        sm.m.w[256 + t] = W2[t];
    }
    __syncthreads();
    {
        int n = b * BLK + t;
        if (n < N_NODES) {
            int r = n / RANGE;
            int local = n - r * RANGE;
            int qword = local >> 2, qsh = (local & 3) * 8;
            float s = 0.0f; unsigned c = 0u;
            for (int mm = 0; mm < M_NODE; ++mm) {
                int blk = (r << 5) + mm;
                s += PS_n[(size_t)blk * RANGE + local];
                c += (PC_n[(size_t)blk * (RANGE / 4) + qword] >> qsh) & 0xFFu;
            }
            float dinv = (c > 0u) ? (1.0f / (float)c) : 0.0f;
            Dinv[n] = dinv;
            float tt = s * dinv;
            float acc = 0.0f;
            #pragma unroll
            for (int f = 0; f < 128; ++f) {
                float h = fmaf(tt, sm.m.w[f], sm.m.w[128 + f]);
                h = fmaxf(h, 0.0f);
                acc = fmaf(h, sm.m.w[256 + f], acc);
            }
            y[n] = acc;
        }
    }
    grid.sync();

    // ============ Phase 4: edge agg 2 (scan binned, gather y) ============
    {
        for (int j = t; j < N_EDGES; j += BLK) sm.e.sS[j] = 0.0f;
        if (t < NR) sm.e.cnt[t] = cursor[t];
        __syncthreads();
        const int TOT = NR * CAP;
        for (int j = b * BLK + t; j < TOT; j += G * BLK) {
            int r   = j / CAP;              // const divisor -> magic mul
            int pos = j - r * CAP;
            if ((unsigned)pos < sm.e.cnt[r]) {
                unsigned w = binned[j];
                int n = r * RANGE + (int)(w >> 14);
                atomicAdd(&sm.e.sS[w & 0x3FFFu], y[n]);
            }
        }
        __syncthreads();
        float* ps = P_S + (size_t)b * N_EDGES;
        for (int j = t; j < N_EDGES; j += BLK) ps[j] = sm.e.sS[j];
    }
    grid.sync();

    // ============ Phase 5: edge reduce 2 -> v2 ============
    if (b < EBLKS) {
        const int eo = t & 63, sl = t >> 6;
        const int e = b * 64 + eo;
        float s = 0.0f;
        if (e < N_EDGES)
            for (int g = sl; g < G; g += 16) s += P_S[(size_t)g * N_EDGES + e];
        sm.m.redS[sl][eo] = s;
        __syncthreads();
        if (sl == 0 && e < N_EDGES) {
            float ss = 0.0f;
            #pragma unroll
            for (int k = 0; k < 16; ++k) ss += sm.m.redS[k][eo];
            v2[e] = ss * Binv[e];
        }
    }
    grid.sync();

    // ============ Phase 6: node pass 2 ============
    {
        const int r  = b >> 5;
        const int mb = b & 31;
        for (int j = t; j < RANGE; j += BLK) sm.n.sS[j] = 0.0f;
        __syncthreads();
        const int cnt = (int)cursor[r];
        const int sub = (cnt + M_NODE - 1) >> 5;
        const int p0 = mb * sub;
        const int p1 = min(p0 + sub, cnt);
        const unsigned* src = binned + (size_t)r * CAP;
        for (int i = p0 + t; i < p1; i += BLK) {
            unsigned w = src[i];
            atomicAdd(&sm.n.sS[w >> 14], v2[w & 0x3FFFu]);
        }
        __syncthreads();
        float* ps = PS_n + (size_t)b * RANGE;
        for (int j = t; j < RANGE; j += BLK) ps[j] = sm.n.sS[j];
    }
    grid.sync();

    // ============ Phase 7: final reduce + bias -> out ============
    {
        int n = b * BLK + t;
        if (n < N_NODES) {
            int r = n / RANGE;
            int local = n - r * RANGE;
            float s = 0.0f;
            for (int mm = 0; mm < M_NODE; ++mm)
                s += PS_n[(size_t)((r << 5) + mm) * RANGE + local];
            out[n] = fmaf(s, Dinv[n], b2[0]);
        }
    }
}

extern "C" void kernel_launch(void* const* d_in, const int* in_sizes, int n_in,
                              void* d_out, int out_size, void* d_ws, size_t ws_size,
                              hipStream_t stream) {
    const float* x    = (const float*)d_in[0];
    const float* W1   = (const float*)d_in[1];
    const float* b1   = (const float*)d_in[2];
    const float* W2   = (const float*)d_in[3];
    const float* b2   = (const float*)d_in[4];
    const int*   nidx = (const int*)d_in[5];
    const int*   eidx = (const int*)d_in[6];
    float*       out  = (float*)d_out;

    char* ws = (char*)d_ws;
    unsigned* binned = (unsigned*)(ws + 0);
    unsigned* cursor = (unsigned*)(ws + 6553600);
    float*    P_S    = (float*)(ws + 6553664);
    unsigned* P_B    = (unsigned*)(ws + 6553664 + 10240000);
    float*    PS_n   = (float*)(ws + 6553664 + 15360000);
    unsigned* PC_n   = (unsigned*)(ws + 6553664 + 28160000);
    float*    smalls = (float*)(ws + 6553664 + 31360000);
    float* Binv = smalls;
    float* v1   = Binv + N_EDGES;
    float* v2   = v1 + N_EDGES;
    float* Dinv = v2 + N_EDGES;
    float* y    = Dinv + N_NODES;

    hipMemsetAsync(cursor, 0, NR * sizeof(unsigned), stream);

    void* args[] = {
        (void*)&nidx, (void*)&eidx, (void*)&x,
        (void*)&W1, (void*)&b1, (void*)&W2, (void*)&b2,
        (void*)&cursor, (void*)&binned,
        (void*)&P_S, (void*)&P_B, (void*)&PS_n, (void*)&PC_n,
        (void*)&Binv, (void*)&v1, (void*)&v2, (void*)&Dinv, (void*)&y,
        (void*)&out
    };
    hipLaunchCooperativeKernel((void*)k_mega, dim3(G), dim3(BLK), args, 0, stream);
}

// Round 7
// 84.389 us; speedup vs baseline: 3.6987x; 3.6987x over previous
//
#include <hip/hip_runtime.h>

static constexpr int N_NODES = 100000;
static constexpr int N_EDGES = 10000;
static constexpr int NNZ     = 1600000;

static constexpr int G1    = 256;          // scatter blocks
static constexpr int CHUNK = NNZ / G1;     // 6250
static constexpr int NRN   = 250;          // node ranges
static constexpr int RN    = 400;          // nodes per range
static constexpr int NRE   = 250;          // edge ranges
static constexpr int RE    = 40;           // edges per range
static constexpr int SLOT  = 64;           // entries per (range, scatter-block) slot; mean 25, 7.8 sigma
static constexpr int BLK   = 1024;

// ---------------- ws layout (bytes), ~34 MB ----------------
// binN @ 0           : NRN*G1*SLOT u32 = 16,384,000   (node-range bins)
// binE @ 16,384,000  : NRE*G1*SLOT u32 = 16,384,000   (edge-range bins)
// cntN @ 32,768,000  : NRN*G1 u32      = 256,000
// cntE @ 33,024,000  : NRE*G1 u32      = 256,000
// v1   @ 33,280,000  : 10K f;  v2 +40,000; Binv +80,000; Dinv +120,000 (100K f); y +520,000 (100K f)
// No buffer is read before being written in the same call (slots guarded by counts) -> poison-safe.

// K1: deterministic-slot counting scatter. No global cursors, no memset.
__global__ __launch_bounds__(BLK) void k_bin(
        const int* __restrict__ nidx, const int* __restrict__ eidx,
        unsigned* __restrict__ binN, unsigned* __restrict__ binE,
        unsigned* __restrict__ cntN, unsigned* __restrict__ cntE) {
    __shared__ unsigned cN[NRN], cE[NRE];
    for (int j = threadIdx.x; j < NRN; j += BLK) cN[j] = 0u;
    for (int j = threadIdx.x; j < NRE; j += BLK) cE[j] = 0u;
    __syncthreads();
    const int b = blockIdx.x;
    const int i0 = b * CHUNK, i1 = i0 + CHUNK;
    for (int i = i0 + threadIdx.x; i < i1; i += BLK) {
        int n = nidx[i], e = eidx[i];
        int rn = n / RN;                      // magic-mul
        int re = e / RE;
        unsigned pn = atomicAdd(&cN[rn], 1u);
        unsigned pe = atomicAdd(&cE[re], 1u);
        binN[((size_t)rn * G1 + b) * SLOT + pn] = ((unsigned)(n - rn * RN) << 14) | (unsigned)e;
        binE[((size_t)re * G1 + b) * SLOT + pe] = ((unsigned)(e - re * RE) << 17) | (unsigned)n;
    }
    __syncthreads();
    for (int j = threadIdx.x; j < NRN; j += BLK) cntN[(size_t)j * G1 + b] = cN[j];
    for (int j = threadIdx.x; j < NRE; j += BLK) cntE[(size_t)j * G1 + b] = cE[j];
}

// K2: edge pass 1 — block owns 40 edges; gather x, accumulate, emit Binv & v1 directly.
__global__ __launch_bounds__(BLK) void k_edge1(
        const unsigned* __restrict__ binE, const unsigned* __restrict__ cntE,
        const float* __restrict__ x,
        float* __restrict__ Binv, float* __restrict__ v1) {
    __shared__ float    sS[RE];
    __shared__ unsigned sC[RE];
    __shared__ unsigned scnt[G1];
    if (threadIdx.x < RE) { sS[threadIdx.x] = 0.0f; sC[threadIdx.x] = 0u; }
    if (threadIdx.x < G1) scnt[threadIdx.x] = cntE[(size_t)blockIdx.x * G1 + threadIdx.x];
    __syncthreads();
    const unsigned* base = binE + (size_t)blockIdx.x * G1 * SLOT;
    for (int j = threadIdx.x; j < G1 * SLOT; j += BLK) {
        int s = j & (SLOT - 1), bb = j >> 6;
        if ((unsigned)s < scnt[bb]) {
            unsigned w = base[j];
            unsigned el = w >> 17;
            unsigned n  = w & 0x1FFFFu;
            atomicAdd(&sS[el], x[n]);
            atomicAdd(&sC[el], 1u);
        }
    }
    __syncthreads();
    if (threadIdx.x < RE) {
        unsigned c = sC[threadIdx.x];
        float binv = (c > 0u) ? (1.0f / (float)c) : 0.0f;
        int e = blockIdx.x * RE + threadIdx.x;
        Binv[e] = binv;
        v1[e]   = sS[threadIdx.x] * binv;
    }
}

// K3: node pass 1 — block owns 400 nodes; stage v1 in LDS, accumulate, fuse Dinv + MLP -> y.
__global__ __launch_bounds__(BLK) void k_node1_mlp(
        const unsigned* __restrict__ binN, const unsigned* __restrict__ cntN,
        const float* __restrict__ v1,
        const float* __restrict__ W1, const float* __restrict__ b1,
        const float* __restrict__ W2,
        float* __restrict__ Dinv, float* __restrict__ y) {
    __shared__ float    sV[N_EDGES];   // 40 KB staged v1
    __shared__ float    sS[RN];
    __shared__ unsigned sC[RN];
    __shared__ unsigned scnt[G1];
    __shared__ float    wgt[384];
    for (int j = threadIdx.x; j < N_EDGES; j += BLK) sV[j] = v1[j];
    if (threadIdx.x < RN) { sS[threadIdx.x] = 0.0f; sC[threadIdx.x] = 0u; }
    if (threadIdx.x < G1) scnt[threadIdx.x] = cntN[(size_t)blockIdx.x * G1 + threadIdx.x];
    if (threadIdx.x < 128) {
        wgt[threadIdx.x]       = W1[threadIdx.x];
        wgt[128 + threadIdx.x] = b1[threadIdx.x];
        wgt[256 + threadIdx.x] = W2[threadIdx.x];
    }
    __syncthreads();
    const unsigned* base = binN + (size_t)blockIdx.x * G1 * SLOT;
    for (int j = threadIdx.x; j < G1 * SLOT; j += BLK) {
        int s = j & (SLOT - 1), bb = j >> 6;
        if ((unsigned)s < scnt[bb]) {
            unsigned w = base[j];
            unsigned nl = w >> 14;
            atomicAdd(&sS[nl], sV[w & 0x3FFFu]);
            atomicAdd(&sC[nl], 1u);
        }
    }
    __syncthreads();
    if (threadIdx.x < RN) {
        unsigned c = sC[threadIdx.x];
        float dinv = (c > 0u) ? (1.0f / (float)c) : 0.0f;
        int n = blockIdx.x * RN + threadIdx.x;
        Dinv[n] = dinv;
        float tt = sS[threadIdx.x] * dinv;
        float acc = 0.0f;
        #pragma unroll
        for (int f = 0; f < 128; ++f) {
            float h = fmaf(tt, wgt[f], wgt[128 + f]);
            h = fmaxf(h, 0.0f);
            acc = fmaf(h, wgt[256 + f], acc);
        }
        y[n] = acc;
    }
}

// K4: edge pass 2 — gather y, accumulate, v2 = sum * Binv.
__global__ __launch_bounds__(BLK) void k_edge2(
        const unsigned* __restrict__ binE, const unsigned* __restrict__ cntE,
        const float* __restrict__ y, const float* __restrict__ Binv,
        float* __restrict__ v2) {
    __shared__ float    sS[RE];
    __shared__ unsigned scnt[G1];
    if (threadIdx.x < RE) sS[threadIdx.x] = 0.0f;
    if (threadIdx.x < G1) scnt[threadIdx.x] = cntE[(size_t)blockIdx.x * G1 + threadIdx.x];
    __syncthreads();
    const unsigned* base = binE + (size_t)blockIdx.x * G1 * SLOT;
    for (int j = threadIdx.x; j < G1 * SLOT; j += BLK) {
        int s = j & (SLOT - 1), bb = j >> 6;
        if ((unsigned)s < scnt[bb]) {
            unsigned w = base[j];
            atomicAdd(&sS[w >> 17], y[w & 0x1FFFFu]);
        }
    }
    __syncthreads();
    if (threadIdx.x < RE) {
        int e = blockIdx.x * RE + threadIdx.x;
        v2[e] = sS[threadIdx.x] * Binv[e];
    }
}

// K5: node pass 2 — stage v2, accumulate, out = sum * Dinv + b2.
__global__ __launch_bounds__(BLK) void k_node2_final(
        const unsigned* __restrict__ binN, const unsigned* __restrict__ cntN,
        const float* __restrict__ v2, const float* __restrict__ Dinv,
        const float* __restrict__ b2, float* __restrict__ out) {
    __shared__ float    sV[N_EDGES];   // 40 KB staged v2
    __shared__ float    sS[RN];
    __shared__ unsigned scnt[G1];
    for (int j = threadIdx.x; j < N_EDGES; j += BLK) sV[j] = v2[j];
    if (threadIdx.x < RN) sS[threadIdx.x] = 0.0f;
    if (threadIdx.x < G1) scnt[threadIdx.x] = cntN[(size_t)blockIdx.x * G1 + threadIdx.x];
    __syncthreads();
    const unsigned* base = binN + (size_t)blockIdx.x * G1 * SLOT;
    for (int j = threadIdx.x; j < G1 * SLOT; j += BLK) {
        int s = j & (SLOT - 1), bb = j >> 6;
        if ((unsigned)s < scnt[bb]) {
            unsigned w = base[j];
            atomicAdd(&sS[w >> 14], sV[w & 0x3FFFu]);
        }
    }
    __syncthreads();
    if (threadIdx.x < RN) {
        int n = blockIdx.x * RN + threadIdx.x;
        out[n] = fmaf(sS[threadIdx.x], Dinv[n], b2[0]);
    }
}

extern "C" void kernel_launch(void* const* d_in, const int* in_sizes, int n_in,
                              void* d_out, int out_size, void* d_ws, size_t ws_size,
                              hipStream_t stream) {
    const float* x    = (const float*)d_in[0];
    const float* W1   = (const float*)d_in[1];
    const float* b1   = (const float*)d_in[2];
    const float* W2   = (const float*)d_in[3];
    const float* b2   = (const float*)d_in[4];
    const int*   nidx = (const int*)d_in[5];
    const int*   eidx = (const int*)d_in[6];
    float*       out  = (float*)d_out;

    char* ws = (char*)d_ws;
    unsigned* binN = (unsigned*)(ws + 0);
    unsigned* binE = (unsigned*)(ws + 16384000);
    unsigned* cntN = (unsigned*)(ws + 32768000);
    unsigned* cntE = (unsigned*)(ws + 33024000);
    float*    v1   = (float*)(ws + 33280000);
    float*    v2   = v1 + N_EDGES;
    float*    Binv = v2 + N_EDGES;
    float*    Dinv = Binv + N_EDGES;
    float*    y    = Dinv + N_NODES;

    k_bin          <<<G1,  BLK, 0, stream>>>(nidx, eidx, binN, binE, cntN, cntE);
    k_edge1        <<<NRE, BLK, 0, stream>>>(binE, cntE, x, Binv, v1);
    k_node1_mlp    <<<NRN, BLK, 0, stream>>>(binN, cntN, v1, W1, b1, W2, Dinv, y);
    k_edge2        <<<NRE, BLK, 0, stream>>>(binE, cntE, y, Binv, v2);
    k_node2_final  <<<NRN, BLK, 0, stream>>>(binN, cntN, v2, Dinv, b2, out);
}

// Round 8
// 83.918 us; speedup vs baseline: 3.7194x; 1.0056x over previous
//
#include <hip/hip_runtime.h>

static constexpr int N_NODES = 100000;
static constexpr int N_EDGES = 10000;
static constexpr int NNZ     = 1600000;

static constexpr int G1    = 256;          // scatter blocks
static constexpr int CHUNK = NNZ / G1;     // 6250
static constexpr int NRN   = 250;          // node ranges
static constexpr int RN    = 400;          // nodes per range
static constexpr int NRE   = 250;          // edge ranges
static constexpr int RE    = 40;           // edges per range
static constexpr int SLOT  = 64;           // entries per (range, scatter-block) slot; mean 25, 7.8 sigma
static constexpr int BLK   = 1024;
static constexpr int NW    = BLK / 64;     // 16 waves per block

// ---------------- ws layout (bytes), ~34 MB ----------------
// binN @ 0           : NRN*G1*SLOT u32 = 16,384,000
// binE @ 16,384,000  : NRE*G1*SLOT u32 = 16,384,000
// cntN @ 32,768,000  : NRN*G1 u32      = 256,000
// cntE @ 33,024,000  : NRE*G1 u32      = 256,000
// v1   @ 33,280,000  : 10K f; v2 +40,000; Binv +80,000; Dinv +120,000 (100K f); y +520,000 (100K f)
// Slots guarded by counts -> poison-safe (no read-before-write).

// K1: deterministic-slot counting scatter. No global cursors, no memset.
__global__ __launch_bounds__(BLK) void k_bin(
        const int* __restrict__ nidx, const int* __restrict__ eidx,
        unsigned* __restrict__ binN, unsigned* __restrict__ binE,
        unsigned* __restrict__ cntN, unsigned* __restrict__ cntE) {
    __shared__ unsigned cN[NRN], cE[NRE];
    for (int j = threadIdx.x; j < NRN; j += BLK) cN[j] = 0u;
    for (int j = threadIdx.x; j < NRE; j += BLK) cE[j] = 0u;
    __syncthreads();
    const int b = blockIdx.x;
    const int i0 = b * CHUNK, i1 = i0 + CHUNK;
    for (int i = i0 + threadIdx.x; i < i1; i += BLK) {
        int n = nidx[i], e = eidx[i];
        int rn = n / RN;                      // magic-mul
        int re = e / RE;
        unsigned pn = atomicAdd(&cN[rn], 1u);
        unsigned pe = atomicAdd(&cE[re], 1u);
        binN[((size_t)rn * G1 + b) * SLOT + pn] = ((unsigned)(n - rn * RN) << 14) | (unsigned)e;
        binE[((size_t)re * G1 + b) * SLOT + pe] = ((unsigned)(e - re * RE) << 17) | (unsigned)n;
    }
    __syncthreads();
    for (int j = threadIdx.x; j < NRN; j += BLK) cntN[(size_t)j * G1 + b] = cN[j];
    for (int j = threadIdx.x; j < NRE; j += BLK) cntE[(size_t)j * G1 + b] = cE[j];
}

// K2: edge pass 1 — per-WAVE privatized accumulators (kills 160-way same-address chains).
__global__ __launch_bounds__(BLK) void k_edge1(
        const unsigned* __restrict__ binE, const unsigned* __restrict__ cntE,
        const float* __restrict__ x,
        float* __restrict__ Binv, float* __restrict__ v1) {
    __shared__ float    sS[NW][RE];
    __shared__ unsigned sC[NW][RE];
    __shared__ unsigned scnt[G1];
    const int t = threadIdx.x;
    for (int j = t; j < NW * RE; j += BLK) { ((float*)sS)[j] = 0.0f; ((unsigned*)sC)[j] = 0u; }
    if (t < G1) scnt[t] = cntE[(size_t)blockIdx.x * G1 + t];
    __syncthreads();
    const int wv = t >> 6;
    const unsigned* base = binE + (size_t)blockIdx.x * G1 * SLOT;
    for (int j = t; j < G1 * SLOT; j += BLK) {
        int s = j & (SLOT - 1), bb = j >> 6;
        if ((unsigned)s < scnt[bb]) {
            unsigned w = base[j];
            unsigned el = w >> 17;
            unsigned n  = w & 0x1FFFFu;
            atomicAdd(&sS[wv][el], x[n]);
            atomicAdd(&sC[wv][el], 1u);
        }
    }
    __syncthreads();
    if (t < RE) {
        float s = 0.0f; unsigned c = 0u;
        #pragma unroll
        for (int k = 0; k < NW; ++k) { s += sS[k][t]; c += sC[k][t]; }
        float binv = (c > 0u) ? (1.0f / (float)c) : 0.0f;
        int e = blockIdx.x * RE + t;
        Binv[e] = binv;
        v1[e]   = s * binv;
    }
}

// K3: node pass 1 — block owns 400 nodes; stage v1 in LDS, accumulate, fuse Dinv + MLP -> y.
__global__ __launch_bounds__(BLK) void k_node1_mlp(
        const unsigned* __restrict__ binN, const unsigned* __restrict__ cntN,
        const float* __restrict__ v1,
        const float* __restrict__ W1, const float* __restrict__ b1,
        const float* __restrict__ W2,
        float* __restrict__ Dinv, float* __restrict__ y) {
    __shared__ float    sV[N_EDGES];   // 40 KB staged v1
    __shared__ float    sS[RN];
    __shared__ unsigned sC[RN];
    __shared__ unsigned scnt[G1];
    __shared__ float    wgt[384];
    for (int j = threadIdx.x; j < N_EDGES; j += BLK) sV[j] = v1[j];
    if (threadIdx.x < RN) { sS[threadIdx.x] = 0.0f; sC[threadIdx.x] = 0u; }
    if (threadIdx.x < G1) scnt[threadIdx.x] = cntN[(size_t)blockIdx.x * G1 + threadIdx.x];
    if (threadIdx.x < 128) {
        wgt[threadIdx.x]       = W1[threadIdx.x];
        wgt[128 + threadIdx.x] = b1[threadIdx.x];
        wgt[256 + threadIdx.x] = W2[threadIdx.x];
    }
    __syncthreads();
    const unsigned* base = binN + (size_t)blockIdx.x * G1 * SLOT;
    for (int j = threadIdx.x; j < G1 * SLOT; j += BLK) {
        int s = j & (SLOT - 1), bb = j >> 6;
        if ((unsigned)s < scnt[bb]) {
            unsigned w = base[j];
            unsigned nl = w >> 14;
            atomicAdd(&sS[nl], sV[w & 0x3FFFu]);
            atomicAdd(&sC[nl], 1u);
        }
    }
    __syncthreads();
    if (threadIdx.x < RN) {
        unsigned c = sC[threadIdx.x];
        float dinv = (c > 0u) ? (1.0f / (float)c) : 0.0f;
        int n = blockIdx.x * RN + threadIdx.x;
        Dinv[n] = dinv;
        float tt = sS[threadIdx.x] * dinv;
        float acc = 0.0f;
        #pragma unroll
        for (int f = 0; f < 128; ++f) {
            float h = fmaf(tt, wgt[f], wgt[128 + f]);
            h = fmaxf(h, 0.0f);
            acc = fmaf(h, wgt[256 + f], acc);
        }
        y[n] = acc;
    }
}

// K4: edge pass 2 — per-wave privatized accumulators; v2 = sum * Binv.
__global__ __launch_bounds__(BLK) void k_edge2(
        const unsigned* __restrict__ binE, const unsigned* __restrict__ cntE,
        const float* __restrict__ y, const float* __restrict__ Binv,
        float* __restrict__ v2) {
    __shared__ float    sS[NW][RE];
    __shared__ unsigned scnt[G1];
    const int t = threadIdx.x;
    for (int j = t; j < NW * RE; j += BLK) ((float*)sS)[j] = 0.0f;
    if (t < G1) scnt[t] = cntE[(size_t)blockIdx.x * G1 + t];
    __syncthreads();
    const int wv = t >> 6;
    const unsigned* base = binE + (size_t)blockIdx.x * G1 * SLOT;
    for (int j = t; j < G1 * SLOT; j += BLK) {
        int s = j & (SLOT - 1), bb = j >> 6;
        if ((unsigned)s < scnt[bb]) {
            unsigned w = base[j];
            atomicAdd(&sS[wv][w >> 17], y[w & 0x1FFFFu]);
        }
    }
    __syncthreads();
    if (t < RE) {
        float s = 0.0f;
        #pragma unroll
        for (int k = 0; k < NW; ++k) s += sS[k][t];
        int e = blockIdx.x * RE + t;
        v2[e] = s * Binv[e];
    }
}

// K5: node pass 2 — stage v2, accumulate, out = sum * Dinv + b2.
__global__ __launch_bounds__(BLK) void k_node2_final(
        const unsigned* __restrict__ binN, const unsigned* __restrict__ cntN,
        const float* __restrict__ v2, const float* __restrict__ Dinv,
        const float* __restrict__ b2, float* __restrict__ out) {
    __shared__ float    sV[N_EDGES];   // 40 KB staged v2
    __shared__ float    sS[RN];
    __shared__ unsigned scnt[G1];
    for (int j = threadIdx.x; j < N_EDGES; j += BLK) sV[j] = v2[j];
    if (threadIdx.x < RN) sS[threadIdx.x] = 0.0f;
    if (threadIdx.x < G1) scnt[threadIdx.x] = cntN[(size_t)blockIdx.x * G1 + threadIdx.x];
    __syncthreads();
    const unsigned* base = binN + (size_t)blockIdx.x * G1 * SLOT;
    for (int j = threadIdx.x; j < G1 * SLOT; j += BLK) {
        int s = j & (SLOT - 1), bb = j >> 6;
        if ((unsigned)s < scnt[bb]) {
            unsigned w = base[j];
            atomicAdd(&sS[w >> 14], sV[w & 0x3FFFu]);
        }
    }
    __syncthreads();
    if (threadIdx.x < RN) {
        int n = blockIdx.x * RN + threadIdx.x;
        out[n] = fmaf(sS[threadIdx.x], Dinv[n], b2[0]);
    }
}

extern "C" void kernel_launch(void* const* d_in, const int* in_sizes, int n_in,
                              void* d_out, int out_size, void* d_ws, size_t ws_size,
                              hipStream_t stream) {
    const float* x    = (const float*)d_in[0];
    const float* W1   = (const float*)d_in[1];
    const float* b1   = (const float*)d_in[2];
    const float* W2   = (const float*)d_in[3];
    const float* b2   = (const float*)d_in[4];
    const int*   nidx = (const int*)d_in[5];
    const int*   eidx = (const int*)d_in[6];
    float*       out  = (float*)d_out;

    char* ws = (char*)d_ws;
    unsigned* binN = (unsigned*)(ws + 0);
    unsigned* binE = (unsigned*)(ws + 16384000);
    unsigned* cntN = (unsigned*)(ws + 32768000);
    unsigned* cntE = (unsigned*)(ws + 33024000);
    float*    v1   = (float*)(ws + 33280000);
    float*    v2   = v1 + N_EDGES;
    float*    Binv = v2 + N_EDGES;
    float*    Dinv = Binv + N_EDGES;
    float*    y    = Dinv + N_NODES;

    k_bin          <<<G1,  BLK, 0, stream>>>(nidx, eidx, binN, binE, cntN, cntE);
    k_edge1        <<<NRE, BLK, 0, stream>>>(binE, cntE, x, Binv, v1);
    k_node1_mlp    <<<NRN, BLK, 0, stream>>>(binN, cntN, v1, W1, b1, W2, Dinv, y);
    k_edge2        <<<NRE, BLK, 0, stream>>>(binE, cntE, y, Binv, v2);
    k_node2_final  <<<NRN, BLK, 0, stream>>>(binN, cntN, v2, Dinv, b2, out);
}